// Round 12
// baseline (118.630 us; speedup 1.0000x reference)
//
#include <hip/hip_runtime.h>
#include <cmath>

// DotMaskLayer: B=16384, D=256, H=64, M=128.
// keep(j) = (j < K) | (128 <= j < 128+K)  [j=256 bias iff K>128; K<=128 in data]
// out[b,h] = tanh( sum_j keep(j)*Y[b,j]*W[b,j,h] ),  W = AUX.reshape(B,257,64)
//
// R12: R11 with DE-INTERLEAVED SIDES. All prior variants alternate side-1
// chunk / side-2 mirror (+32KB) per request -> two streams ping-ponging DRAM
// pages. Here each wave walks its contiguous chunk range twice: pass 1 = rows
// [4lo, 4hi) ascending, pass 2 = +128 mirror ascending. Purely ascending
// address stream per pass, same bytes / masks / quantization as R11.
// Last live theory for the 113us-vs-90us gap.

#define D_DIM 256
#define H_DIM 64
#define ROWS 257
#define ROWSTRIDE (ROWS * H_DIM)   // 16448 floats per batch row of AUX

__global__ __launch_bounds__(256, 8)
void dotmask_kernel(const float* __restrict__ X,
                    const float* __restrict__ AUX,
                    const int* __restrict__ K,
                    float* __restrict__ out)
{
    const int b    = blockIdx.x;
    const int tid  = threadIdx.x;
    const int lane = tid & 63;
    const int w    = tid >> 6;          // wave id 0..3 (all share row b)
    const int jo   = lane >> 4;         // row offset within 4-row chunk
    const int h4   = (lane & 15) * 4;   // this lane's 4 consecutive h's

    const int k = K[b];
    const float* __restrict__ Wb  = AUX + (size_t)b * ROWSTRIDE;
    const float* __restrict__ WbH = Wb + h4;
    const float* __restrict__ Xb  = X   + (size_t)b * D_DIM;

    float ax = 0.f, ay = 0.f, az = 0.f, aw = 0.f;

    // chunk c covers rows [4c,4c+4). Wave w owns contiguous [lo, hi).
    const int C  = (k + 3) >> 2;
    const int lo = (C * w) >> 2;
    const int hi = (C * (w + 1)) >> 2;

    // ---- pass 1: side 1, rows [4lo, 4hi) ascending, 2 chunks/iter ----
    for (int c = lo; c < hi; c += 2) {
        const int ja = 4 * c + jo;                 // <= 4C-1 <= k+2 <= 130
        const float4 wa = *reinterpret_cast<const float4*>(WbH + ((size_t)ja << 6));
        const float  xar = Xb[ja];

        const bool doB = (c + 1 < hi);
        float4 wb = make_float4(0,0,0,0);
        float  xbr = 0.f;
        int jb = 0;
        if (doB) {
            jb  = 4 * (c + 1) + jo;
            wb  = *reinterpret_cast<const float4*>(WbH + ((size_t)jb << 6));
            xbr = Xb[jb];
        }

        const float xa = (ja < k) ? xar : 0.f;
        ax += xa * wa.x; ay += xa * wa.y; az += xa * wa.z; aw += xa * wa.w;
        const float xb = (doB && jb < k) ? xbr : 0.f;
        ax += xb * wb.x; ay += xb * wb.y; az += xb * wb.z; aw += xb * wb.w;
    }

    // ---- pass 2: side 2, rows +128, ascending, 2 chunks/iter ----
    for (int c = lo; c < hi; c += 2) {
        const int ja  = 4 * c + jo;
        const int ja2 = (ja + 128 > 256) ? 256 : (ja + 128);   // clamp (masked)
        const float4 wa = *reinterpret_cast<const float4*>(WbH + ((size_t)ja2 << 6));
        const float  xar = Xb[(ja + 128 > 255) ? 255 : (ja + 128)];

        const bool doB = (c + 1 < hi);
        float4 wb = make_float4(0,0,0,0);
        float  xbr = 0.f;
        int jb = 0;
        if (doB) {
            jb = 4 * (c + 1) + jo;
            const int jb2 = (jb + 128 > 256) ? 256 : (jb + 128);
            wb  = *reinterpret_cast<const float4*>(WbH + ((size_t)jb2 << 6));
            xbr = Xb[(jb + 128 > 255) ? 255 : (jb + 128)];
        }

        const float xa = (ja < k) ? xar : 0.f;
        ax += xa * wa.x; ay += xa * wa.y; az += xa * wa.z; aw += xa * wa.w;
        const float xb = (doB && jb < k) ? xbr : 0.f;
        ax += xb * wb.x; ay += xb * wb.y; az += xb * wb.z; aw += xb * wb.w;
    }

    // bias row j=256 (kept iff k > 128; never with this data, kept for generality)
    if (k > 128 && w == 0 && jo == 0) {
        const float4 wv = *reinterpret_cast<const float4*>(Wb + (size_t)256 * H_DIM + h4);
        ax += wv.x; ay += wv.y; az += wv.z; aw += wv.w;
    }

    // reduce across the 4 jo-groups (lanes l, l+16, l+32, l+48 share h4)
    ax += __shfl_xor(ax, 16); ay += __shfl_xor(ay, 16);
    az += __shfl_xor(az, 16); aw += __shfl_xor(aw, 16);
    ax += __shfl_xor(ax, 32); ay += __shfl_xor(ay, 32);
    az += __shfl_xor(az, 32); aw += __shfl_xor(aw, 32);

    // combine the 4 waves' partials via LDS
    __shared__ float lds[4][H_DIM];
    if (lane < 16) {
        float4 p; p.x = ax; p.y = ay; p.z = az; p.w = aw;
        *reinterpret_cast<float4*>(&lds[w][h4]) = p;
    }
    __syncthreads();

    if (tid < H_DIM) {
        const float s = lds[0][tid] + lds[1][tid] + lds[2][tid] + lds[3][tid];
        out[(size_t)b * H_DIM + tid] = tanhf(s);
    }
}

extern "C" void kernel_launch(void* const* d_in, const int* in_sizes, int n_in,
                              void* d_out, int out_size, void* d_ws, size_t ws_size,
                              hipStream_t stream)
{
    const float* X   = (const float*)d_in[0];
    const float* AUX = (const float*)d_in[1];
    const int*   K   = (const int*)d_in[2];
    float* out = (float*)d_out;

    const int B = in_sizes[2];                 // 16384
    dotmask_kernel<<<B, 256, 0, stream>>>(X, AUX, K, out);
}

// Round 13
// 112.612 us; speedup vs baseline: 1.0534x; 1.0534x over previous
//
#include <hip/hip_runtime.h>
#include <cmath>

// DotMaskLayer: B=16384, D=256, H=64, M=128.
// keep(j) = (j < K) | (128 <= j < 128+K)  [j=256 bias iff K>128; K<=128 in data]
// out[b,h] = tanh( sum_j keep(j)*Y[b,j]*W[b,j,h] ),  W = AUX.reshape(B,257,64)
//
// R13: R11 (contiguous per-wave chunk ranges, interleaved sides, 2-chunk
// unroll) + PRE-MASKED X STAGED IN LDS. Staging pass writes
// xm[j] = keep(j,k) ? X[j] : 0 (xm[256]=0), so the inner loop has NO masks,
// NO clamp-selects on X, and NO global X loads: per iteration just 4 W-loads
// + 4 broadcast ds_reads + 16 FMAs. Halves VMEM instruction count and thins
// VALU per 4KB of useful fetch. Tests the instruction-overhead theory; bytes
// and schedule otherwise identical to R11 (113.1us best).

#define D_DIM 256
#define H_DIM 64
#define ROWS 257
#define ROWSTRIDE (ROWS * H_DIM)   // 16448 floats per batch row of AUX

__global__ __launch_bounds__(256, 8)
void dotmask_kernel(const float* __restrict__ X,
                    const float* __restrict__ AUX,
                    const int* __restrict__ K,
                    float* __restrict__ out)
{
    const int b    = blockIdx.x;
    const int tid  = threadIdx.x;
    const int lane = tid & 63;
    const int w    = tid >> 6;          // wave id 0..3 (all share row b)
    const int jo   = lane >> 4;         // row offset within 4-row chunk
    const int h4   = (lane & 15) * 4;   // this lane's 4 consecutive h's

    const int k = K[b];
    const float* __restrict__ Wb  = AUX + (size_t)b * ROWSTRIDE;
    const float* __restrict__ WbH = Wb + h4;
    const float* __restrict__ Xb  = X   + (size_t)b * D_DIM;

    // ---- stage pre-masked X row into LDS (one coalesced load per thread) ----
    __shared__ float xm[ROWS + 3];      // 257 used, padded
    {
        const float xv = Xb[tid];       // tid in [0,256)
        const bool keep = (tid < k) | ((tid >= 128) & (tid < 128 + k));
        xm[tid] = keep ? xv : 0.f;
        if (tid == 0) xm[256] = 0.f;    // clamped-index reads must be zero
    }
    __syncthreads();

    float ax = 0.f, ay = 0.f, az = 0.f, aw = 0.f;

    // chunk c covers rows [4c,4c+4) + mirror (+128). Wave w owns contiguous
    // [lo, hi), hi-lo uniform +-1 across waves.
    const int C  = (k + 3) >> 2;
    const int lo = (C * w) >> 2;
    const int hi = (C * (w + 1)) >> 2;

    for (int c = lo; c < hi; c += 2) {
        // ---- chunk A: rows ja (side 1) and ja+128 (side 2) ----
        const int ja  = 4 * c + jo;                    // <= 130 < 257
        const int ja2 = (ja + 128 > 256) ? 256 : (ja + 128);
        const float4 wa1 = *reinterpret_cast<const float4*>(WbH + ((size_t)ja  << 6));
        const float4 wa2 = *reinterpret_cast<const float4*>(WbH + ((size_t)ja2 << 6));
        const float  xa1 = xm[ja];                     // 0 when ja >= k
        const float  xa2 = xm[ja2];                    // 0 when masked/clamped

        // ---- chunk B (wave-uniform guard: no wasted fetch) ----
        const bool doB = (c + 1 < hi);
        float4 wb1 = make_float4(0,0,0,0), wb2 = make_float4(0,0,0,0);
        float  xb1 = 0.f, xb2 = 0.f;
        if (doB) {
            const int jb  = 4 * (c + 1) + jo;          // <= 130
            const int jb2 = (jb + 128 > 256) ? 256 : (jb + 128);
            wb1 = *reinterpret_cast<const float4*>(WbH + ((size_t)jb  << 6));
            wb2 = *reinterpret_cast<const float4*>(WbH + ((size_t)jb2 << 6));
            xb1 = xm[jb];
            xb2 = xm[jb2];
        }

        // ---- FMAs ----
        ax += xa1 * wa1.x; ay += xa1 * wa1.y; az += xa1 * wa1.z; aw += xa1 * wa1.w;
        ax += xa2 * wa2.x; ay += xa2 * wa2.y; az += xa2 * wa2.z; aw += xa2 * wa2.w;
        ax += xb1 * wb1.x; ay += xb1 * wb1.y; az += xb1 * wb1.z; aw += xb1 * wb1.w;
        ax += xb2 * wb2.x; ay += xb2 * wb2.y; az += xb2 * wb2.z; aw += xb2 * wb2.w;
    }

    // bias row j=256 (kept iff k > 128; never with this data, kept for generality)
    if (k > 128 && w == 0 && jo == 0) {
        const float4 wv = *reinterpret_cast<const float4*>(Wb + (size_t)256 * H_DIM + h4);
        ax += wv.x; ay += wv.y; az += wv.z; aw += wv.w;
    }

    // reduce across the 4 jo-groups (lanes l, l+16, l+32, l+48 share h4)
    ax += __shfl_xor(ax, 16); ay += __shfl_xor(ay, 16);
    az += __shfl_xor(az, 16); aw += __shfl_xor(aw, 16);
    ax += __shfl_xor(ax, 32); ay += __shfl_xor(ay, 32);
    az += __shfl_xor(az, 32); aw += __shfl_xor(aw, 32);

    // combine the 4 waves' partials via LDS
    __shared__ float red[4][H_DIM];
    if (lane < 16) {
        float4 p; p.x = ax; p.y = ay; p.z = az; p.w = aw;
        *reinterpret_cast<float4*>(&red[w][h4]) = p;
    }
    __syncthreads();

    if (tid < H_DIM) {
        const float s = red[0][tid] + red[1][tid] + red[2][tid] + red[3][tid];
        out[(size_t)b * H_DIM + tid] = tanhf(s);
    }
}

extern "C" void kernel_launch(void* const* d_in, const int* in_sizes, int n_in,
                              void* d_out, int out_size, void* d_ws, size_t ws_size,
                              hipStream_t stream)
{
    const float* X   = (const float*)d_in[0];
    const float* AUX = (const float*)d_in[1];
    const int*   K   = (const int*)d_in[2];
    float* out = (float*)d_out;

    const int B = in_sizes[2];                 // 16384
    dotmask_kernel<<<B, 256, 0, stream>>>(X, AUX, K, out);
}

// Round 14
// 99.945 us; speedup vs baseline: 1.1870x; 1.1267x over previous
//
#include <hip/hip_runtime.h>
#include <cmath>

// DotMaskLayer: B=16384, D=256, H=64, M=128.
// keep(j) = (j < K) | (128 <= j < 128+K)  [j=256 bias iff K>128; K<=128 in data]
// out[b,h] = tanh( sum_j keep(j)*Y[b,j]*W[b,j,h] ),  W = AUX.reshape(B,257,64)
//
// R14: R13 (pre-masked X in LDS, contiguous per-wave chunk ranges, 2-chunk
// unroll) + NONTEMPORAL loads on the W stream and nontemporal out store.
// Pure streaming workload (zero reuse): nt bypasses cache allocation, testing
// whether L2/LLC allocation churn throttles the fill path at ~5 TB/s.
// Bytes and schedule identical to R13 (112.6us best).

#define D_DIM 256
#define H_DIM 64
#define ROWS 257
#define ROWSTRIDE (ROWS * H_DIM)   // 16448 floats per batch row of AUX

typedef float vf4 __attribute__((ext_vector_type(4)));

__device__ __forceinline__ vf4 ldnt(const float* p)
{
    return __builtin_nontemporal_load(reinterpret_cast<const vf4*>(p));
}

__global__ __launch_bounds__(256, 8)
void dotmask_kernel(const float* __restrict__ X,
                    const float* __restrict__ AUX,
                    const int* __restrict__ K,
                    float* __restrict__ out)
{
    const int b    = blockIdx.x;
    const int tid  = threadIdx.x;
    const int lane = tid & 63;
    const int w    = tid >> 6;          // wave id 0..3 (all share row b)
    const int jo   = lane >> 4;         // row offset within 4-row chunk
    const int h4   = (lane & 15) * 4;   // this lane's 4 consecutive h's

    const int k = K[b];
    const float* __restrict__ Wb  = AUX + (size_t)b * ROWSTRIDE;
    const float* __restrict__ WbH = Wb + h4;
    const float* __restrict__ Xb  = X   + (size_t)b * D_DIM;

    // ---- stage pre-masked X row into LDS (one coalesced load per thread) ----
    __shared__ float xm[ROWS + 3];      // 257 used, padded
    {
        const float xv = Xb[tid];       // tid in [0,256)
        const bool keep = (tid < k) | ((tid >= 128) & (tid < 128 + k));
        xm[tid] = keep ? xv : 0.f;
        if (tid == 0) xm[256] = 0.f;    // clamped-index reads must be zero
    }
    __syncthreads();

    float ax = 0.f, ay = 0.f, az = 0.f, aw = 0.f;

    // chunk c covers rows [4c,4c+4) + mirror (+128). Wave w owns contiguous
    // [lo, hi), hi-lo uniform +-1 across waves.
    const int C  = (k + 3) >> 2;
    const int lo = (C * w) >> 2;
    const int hi = (C * (w + 1)) >> 2;

    for (int c = lo; c < hi; c += 2) {
        // ---- chunk A: rows ja (side 1) and ja+128 (side 2) ----
        const int ja  = 4 * c + jo;                    // <= 130 < 257
        const int ja2 = (ja + 128 > 256) ? 256 : (ja + 128);
        const vf4 wa1 = ldnt(WbH + ((size_t)ja  << 6));
        const vf4 wa2 = ldnt(WbH + ((size_t)ja2 << 6));
        const float xa1 = xm[ja];                      // 0 when ja >= k
        const float xa2 = xm[ja2];                     // 0 when masked/clamped

        // ---- chunk B (wave-uniform guard: no wasted fetch) ----
        const bool doB = (c + 1 < hi);
        vf4 wb1 = (vf4)(0.f), wb2 = (vf4)(0.f);
        float xb1 = 0.f, xb2 = 0.f;
        if (doB) {
            const int jb  = 4 * (c + 1) + jo;          // <= 130
            const int jb2 = (jb + 128 > 256) ? 256 : (jb + 128);
            wb1 = ldnt(WbH + ((size_t)jb  << 6));
            wb2 = ldnt(WbH + ((size_t)jb2 << 6));
            xb1 = xm[jb];
            xb2 = xm[jb2];
        }

        // ---- FMAs ----
        ax += xa1 * wa1[0]; ay += xa1 * wa1[1]; az += xa1 * wa1[2]; aw += xa1 * wa1[3];
        ax += xa2 * wa2[0]; ay += xa2 * wa2[1]; az += xa2 * wa2[2]; aw += xa2 * wa2[3];
        ax += xb1 * wb1[0]; ay += xb1 * wb1[1]; az += xb1 * wb1[2]; aw += xb1 * wb1[3];
        ax += xb2 * wb2[0]; ay += xb2 * wb2[1]; az += xb2 * wb2[2]; aw += xb2 * wb2[3];
    }

    // bias row j=256 (kept iff k > 128; never with this data, kept for generality)
    if (k > 128 && w == 0 && jo == 0) {
        const vf4 wv = ldnt(Wb + (size_t)256 * H_DIM + h4);
        ax += wv[0]; ay += wv[1]; az += wv[2]; aw += wv[3];
    }

    // reduce across the 4 jo-groups (lanes l, l+16, l+32, l+48 share h4)
    ax += __shfl_xor(ax, 16); ay += __shfl_xor(ay, 16);
    az += __shfl_xor(az, 16); aw += __shfl_xor(aw, 16);
    ax += __shfl_xor(ax, 32); ay += __shfl_xor(ay, 32);
    az += __shfl_xor(az, 32); aw += __shfl_xor(aw, 32);

    // combine the 4 waves' partials via LDS
    __shared__ float red[4][H_DIM];
    if (lane < 16) {
        float4 p; p.x = ax; p.y = ay; p.z = az; p.w = aw;
        *reinterpret_cast<float4*>(&red[w][h4]) = p;
    }
    __syncthreads();

    if (tid < H_DIM) {
        const float s = red[0][tid] + red[1][tid] + red[2][tid] + red[3][tid];
        __builtin_nontemporal_store(tanhf(s), out + (size_t)b * H_DIM + tid);
    }
}

extern "C" void kernel_launch(void* const* d_in, const int* in_sizes, int n_in,
                              void* d_out, int out_size, void* d_ws, size_t ws_size,
                              hipStream_t stream)
{
    const float* X   = (const float*)d_in[0];
    const float* AUX = (const float*)d_in[1];
    const int*   K   = (const int*)d_in[2];
    float* out = (float*)d_out;

    const int B = in_sizes[2];                 // 16384
    dotmask_kernel<<<B, 256, 0, stream>>>(X, AUX, K, out);
}

// Round 15
// 98.533 us; speedup vs baseline: 1.2040x; 1.0143x over previous
//
#include <hip/hip_runtime.h>
#include <cmath>

// DotMaskLayer: B=16384, D=256, H=64, M=128.
// keep(j) = (j < K) | (128 <= j < 128+K)  [j=256 bias iff K>128; K<=128 in data]
// out[b,h] = tanh( sum_j keep(j)*Y[b,j]*W[b,j,h] ),  W = AUX.reshape(B,257,64)
//
// R15: R14 (nt W-loads + nt store, pre-masked X in LDS, contiguous per-wave
// ranges, 2-chunk unroll) + EXEC-MASK PREDICATED LOADS:
//  - W loads guarded by per-lane (j < k): masked lanes fetch nothing ->
//    removes the 4-row chunk tail over-fetch (~12.6 MB).
//  - X stage load guarded by keep(tid): halves X fetch (~8.4 MB).
//  - (j<k) => j+128 <= 255, so the +128 clamp is dead and removed.
// Useful-byte floor ~549 MB; R14 = 5.70 TB/s (90.6% of copy ceiling).

#define D_DIM 256
#define H_DIM 64
#define ROWS 257
#define ROWSTRIDE (ROWS * H_DIM)   // 16448 floats per batch row of AUX

typedef float vf4 __attribute__((ext_vector_type(4)));

__device__ __forceinline__ vf4 ldnt(const float* p)
{
    return __builtin_nontemporal_load(reinterpret_cast<const vf4*>(p));
}

__global__ __launch_bounds__(256, 8)
void dotmask_kernel(const float* __restrict__ X,
                    const float* __restrict__ AUX,
                    const int* __restrict__ K,
                    float* __restrict__ out)
{
    const int b    = blockIdx.x;
    const int tid  = threadIdx.x;
    const int lane = tid & 63;
    const int w    = tid >> 6;          // wave id 0..3 (all share row b)
    const int jo   = lane >> 4;         // row offset within 4-row chunk
    const int h4   = (lane & 15) * 4;   // this lane's 4 consecutive h's

    const int k = K[b];
    const float* __restrict__ Wb  = AUX + (size_t)b * ROWSTRIDE;
    const float* __restrict__ WbH = Wb + h4;
    const float* __restrict__ Xb  = X   + (size_t)b * D_DIM;

    // ---- stage pre-masked X row into LDS (exec-masked load: kept only) ----
    __shared__ float xm[ROWS + 3];      // 257 used, padded
    {
        const bool keep = (tid < k) | ((tid >= 128) & (tid < 128 + k));
        float xv = 0.f;
        if (keep) xv = Xb[tid];         // masked lanes fetch nothing
        xm[tid] = xv;
        if (tid == 0) xm[256] = 0.f;
    }
    __syncthreads();

    float ax = 0.f, ay = 0.f, az = 0.f, aw = 0.f;

    // chunk c covers rows [4c,4c+4) + mirror (+128). Wave w owns contiguous
    // [lo, hi), hi-lo uniform +-1 across waves.
    const int C  = (k + 3) >> 2;
    const int lo = (C * w) >> 2;
    const int hi = (C * (w + 1)) >> 2;

    for (int c = lo; c < hi; c += 2) {
        // ---- chunk A: rows ja (side 1) and ja+128 (side 2), predicated ----
        const int ja = 4 * c + jo;
        if (ja < k) {                                  // => ja <= 127, ja+128 <= 255
            const vf4 wa1 = ldnt(WbH + ((size_t)ja         << 6));
            const vf4 wa2 = ldnt(WbH + ((size_t)(ja + 128) << 6));
            const float xa1 = xm[ja];
            const float xa2 = xm[ja + 128];
            ax += xa1 * wa1[0]; ay += xa1 * wa1[1]; az += xa1 * wa1[2]; aw += xa1 * wa1[3];
            ax += xa2 * wa2[0]; ay += xa2 * wa2[1]; az += xa2 * wa2[2]; aw += xa2 * wa2[3];
        }

        // ---- chunk B (wave-range guard + per-lane predication) ----
        if (c + 1 < hi) {
            const int jb = 4 * (c + 1) + jo;
            if (jb < k) {
                const vf4 wb1 = ldnt(WbH + ((size_t)jb         << 6));
                const vf4 wb2 = ldnt(WbH + ((size_t)(jb + 128) << 6));
                const float xb1 = xm[jb];
                const float xb2 = xm[jb + 128];
                ax += xb1 * wb1[0]; ay += xb1 * wb1[1]; az += xb1 * wb1[2]; aw += xb1 * wb1[3];
                ax += xb2 * wb2[0]; ay += xb2 * wb2[1]; az += xb2 * wb2[2]; aw += xb2 * wb2[3];
            }
        }
    }

    // bias row j=256 (kept iff k > 128; never with this data, kept for generality)
    if (k > 128 && w == 0 && jo == 0) {
        const vf4 wv = ldnt(Wb + (size_t)256 * H_DIM + h4);
        ax += wv[0]; ay += wv[1]; az += wv[2]; aw += wv[3];
    }

    // reduce across the 4 jo-groups (lanes l, l+16, l+32, l+48 share h4)
    ax += __shfl_xor(ax, 16); ay += __shfl_xor(ay, 16);
    az += __shfl_xor(az, 16); aw += __shfl_xor(aw, 16);
    ax += __shfl_xor(ax, 32); ay += __shfl_xor(ay, 32);
    az += __shfl_xor(az, 32); aw += __shfl_xor(aw, 32);

    // combine the 4 waves' partials via LDS
    __shared__ float red[4][H_DIM];
    if (lane < 16) {
        float4 p; p.x = ax; p.y = ay; p.z = az; p.w = aw;
        *reinterpret_cast<float4*>(&red[w][h4]) = p;
    }
    __syncthreads();

    if (tid < H_DIM) {
        const float s = red[0][tid] + red[1][tid] + red[2][tid] + red[3][tid];
        __builtin_nontemporal_store(tanhf(s), out + (size_t)b * H_DIM + tid);
    }
}

extern "C" void kernel_launch(void* const* d_in, const int* in_sizes, int n_in,
                              void* d_out, int out_size, void* d_ws, size_t ws_size,
                              hipStream_t stream)
{
    const float* X   = (const float*)d_in[0];
    const float* AUX = (const float*)d_in[1];
    const int*   K   = (const int*)d_in[2];
    float* out = (float*)d_out;

    const int B = in_sizes[2];                 // 16384
    dotmask_kernel<<<B, 256, 0, stream>>>(X, AUX, K, out);
}